// Round 5
// baseline (257.277 us; speedup 1.0000x reference)
//
#include <hip/hip_runtime.h>
#include <hip/hip_bf16.h>

// QuantumFeedForward: out = relu(cos(x[:,:8]) @ W1^T + b1) @ W2^T + b2
//  K0: W2 f32->bf16
//  K1: H = relu(cos-dot) bf16 — TPB=16 (4 blocks/CU), native bf16 cvt
//  K2: 256x256 GEMM, BK=32, 8 waves, triple-buffered LDS, counted vmcnt(4),
//      XOR bank swizzle, XCD-chunked block swizzle.  (unchanged from R4)

#define EMBED 1024
#define FFN   4096
#define NQ    8
#define NTOK  16384        // 4*4096 tokens (M)
#define NDIM  1024         // output embed (N)
#define KDIM  4096         // ffn (K)

#define BM 256
#define BN 256
#define BK 32
#define NT (KDIM / BK)     // 128 K-tiles

typedef __attribute__((ext_vector_type(8))) short short8;   // 8 bf16 = 4 VGPRs
typedef __attribute__((ext_vector_type(8))) unsigned short ushort8;
typedef __attribute__((ext_vector_type(4))) float f32x4;

__device__ __forceinline__ unsigned short f2bf(float f) {
  unsigned u = __float_as_uint(f);
  return (unsigned short)((u + 0x7FFFu + ((u >> 16) & 1u)) >> 16);
}

__device__ __forceinline__ void gload_lds16(const void* g, void* l) {
  __builtin_amdgcn_global_load_lds(
      (const __attribute__((address_space(1))) void*)g,
      (__attribute__((address_space(3))) void*)l, 16, 0, 0);
}

// ---- K0: W2 f32 -> bf16 ---------------------------------------------------
__global__ void w2cvt_kernel(const float* __restrict__ W2,
                             unsigned short* __restrict__ W2b) {
  const size_t idx = (size_t)blockIdx.x * blockDim.x + threadIdx.x;
  const float4 v = *reinterpret_cast<const float4*>(W2 + idx * 4);
  ushort4 o;
  o.x = f2bf(v.x); o.y = f2bf(v.y); o.z = f2bf(v.z); o.w = f2bf(v.w);
  *reinterpret_cast<ushort4*>(W2b + idx * 4) = o;
}

// ---- K1: H = relu(cos(x[:, :8]) @ W1^T + b1) in bf16 ----------------------
// TPB=16 tokens/block -> 1024 blocks (4/CU, full wave occupancy to hide
// store latency). Thread owns 8 consecutive f. Native bf16 casts
// (compiler emits v_cvt_pk_bf16_f32) instead of 4-op manual RNE.
#define TPB 16
__global__ __launch_bounds__(512) void h_kernel(
    const float* __restrict__ x,
    const float* __restrict__ W1,
    const float* __restrict__ b1,
    unsigned short* __restrict__ H) {
  __shared__ float q_lds[TPB][NQ];
  const int tid = threadIdx.x;
  const int t0 = blockIdx.x * TPB;

  if (tid < TPB * 2) {   // 32 threads x float4
    const int t = tid >> 1, half = (tid & 1) * 4;
    const float4 v = *reinterpret_cast<const float4*>(
        x + (size_t)(t0 + t) * EMBED + half);
    q_lds[t][half + 0] = __cosf(v.x);
    q_lds[t][half + 1] = __cosf(v.y);
    q_lds[t][half + 2] = __cosf(v.z);
    q_lds[t][half + 3] = __cosf(v.w);
  }

  const int f8 = tid * 8;
  float w[8][8], bb[8];
#pragma unroll
  for (int j = 0; j < 8; ++j) {
    const float4 lo = *reinterpret_cast<const float4*>(W1 + (size_t)(f8 + j) * NQ);
    const float4 hi = *reinterpret_cast<const float4*>(W1 + (size_t)(f8 + j) * NQ + 4);
    w[j][0] = lo.x; w[j][1] = lo.y; w[j][2] = lo.z; w[j][3] = lo.w;
    w[j][4] = hi.x; w[j][5] = hi.y; w[j][6] = hi.z; w[j][7] = hi.w;
  }
  {
    const float4 lo = *reinterpret_cast<const float4*>(b1 + f8);
    const float4 hi = *reinterpret_cast<const float4*>(b1 + f8 + 4);
    bb[0] = lo.x; bb[1] = lo.y; bb[2] = lo.z; bb[3] = lo.w;
    bb[4] = hi.x; bb[5] = hi.y; bb[6] = hi.z; bb[7] = hi.w;
  }
  __syncthreads();

#pragma unroll 2
  for (int t = 0; t < TPB; ++t) {
    float q[8];
#pragma unroll
    for (int k = 0; k < NQ; ++k) q[k] = q_lds[t][k];
    float hv[8];
#pragma unroll
    for (int j = 0; j < 8; ++j) {
      float h = bb[j];
#pragma unroll
      for (int k = 0; k < NQ; ++k) h = fmaf(q[k], w[j][k], h);
      hv[j] = fmaxf(h, 0.0f);
    }
    __hip_bfloat16 o[8];
#pragma unroll
    for (int j = 0; j < 8; ++j) o[j] = __float2bfloat16(hv[j]);
    *reinterpret_cast<ushort8*>(H + (size_t)(t0 + t) * FFN + f8) =
        *reinterpret_cast<const ushort8*>(o);
  }
}

// ---- K2: out[M,N] = H[M,K] @ W2b[N,K]^T + b2 ------------------------------
// (unchanged from R4 — validated: MfmaUtil 46%, 0 bank conflicts)
__global__ __launch_bounds__(512, 2) void gemm_kernel(
    const unsigned short* __restrict__ H,
    const unsigned short* __restrict__ W2b,
    const float* __restrict__ b2,
    float* __restrict__ out) {
  __shared__ unsigned short lds[3 * 2 * BM * BK];  // 3 bufs x (A,B) x 16KB = 96KB

  const int tid = threadIdx.x;
  const int wg  = blockIdx.x;
  const int swz = (wg & 7) * 32 + (wg >> 3);
  const int bm  = swz >> 2;      // 0..63
  const int bn  = swz & 3;       // 0..3

  const unsigned short* Abase = H   + (size_t)bm * BM * KDIM;
  const unsigned short* Bbase = W2b + (size_t)bn * BN * KDIM;

  const int chA0 = tid, chA1 = tid + 512;
  const int rA0 = chA0 >> 2, cA0 = chA0 & 3;
  const int rA1 = chA1 >> 2, cA1 = chA1 & 3;
  const int src0 = rA0 * KDIM + (cA0 ^ ((rA0 >> 1) & 3)) * 8;
  const int src1 = rA1 * KDIM + (cA1 ^ ((rA1 >> 1) & 3)) * 8;
  const int d0 = chA0 * 8, d1 = chA1 * 8;

  const int lane = tid & 63;
  const int wid  = tid >> 6;     // 8 waves: wr in {0,1}, wc in {0..3}
  const int wr   = wid >> 2;
  const int wc   = wid & 3;
  const int fr   = lane & 15;
  const int fq   = lane >> 4;
  const int coff = (fq ^ ((fr >> 1) & 3)) * 8;  // swizzled k-chunk on read

  int offA[8], offB[4];
#pragma unroll
  for (int m = 0; m < 8; ++m) offA[m] = (wr * 128 + m * 16 + fr) * BK + coff;
#pragma unroll
  for (int n = 0; n < 4; ++n) offB[n] = (wc * 64 + n * 16 + fr) * BK + coff;

  f32x4 acc[8][4];
#pragma unroll
  for (int m = 0; m < 8; ++m)
#pragma unroll
    for (int n = 0; n < 4; ++n) {
      f32x4 z = {0.0f, 0.0f, 0.0f, 0.0f};
      acc[m][n] = z;
    }

  auto STAGE = [&](int t, int buf) {
    unsigned short* La = &lds[buf * (2 * BM * BK)];
    unsigned short* Lb = La + BM * BK;
    const size_t ko = (size_t)t * BK;
    gload_lds16(Abase + ko + src0, La + d0);
    gload_lds16(Abase + ko + src1, La + d1);
    gload_lds16(Bbase + ko + src0, Lb + d0);
    gload_lds16(Bbase + ko + src1, Lb + d1);
  };

  STAGE(0, 0);
  STAGE(1, 1);
  asm volatile("s_waitcnt vmcnt(4)" ::: "memory");
  __builtin_amdgcn_s_barrier();

  int bufc = 0;
  int bufs = 2;
#pragma unroll 1
  for (int t = 0; t < NT; ++t) {
    if (t + 2 < NT) STAGE(t + 2, bufs);
    const unsigned short* La = &lds[bufc * (2 * BM * BK)];
    const unsigned short* Lb = La + BM * BK;
    short8 a[8], b[4];
#pragma unroll
    for (int m = 0; m < 8; ++m)
      a[m] = *reinterpret_cast<const short8*>(La + offA[m]);
#pragma unroll
    for (int n = 0; n < 4; ++n)
      b[n] = *reinterpret_cast<const short8*>(Lb + offB[n]);
    __builtin_amdgcn_s_setprio(1);
#pragma unroll
    for (int m = 0; m < 8; ++m)
#pragma unroll
      for (int n = 0; n < 4; ++n)
        acc[m][n] = __builtin_amdgcn_mfma_f32_16x16x32_bf16(
            a[m], b[n], acc[m][n], 0, 0, 0);
    __builtin_amdgcn_s_setprio(0);
    if (t < NT - 2) {
      asm volatile("s_waitcnt vmcnt(4)" ::: "memory");
      __builtin_amdgcn_s_barrier();
    } else if (t == NT - 2) {
      asm volatile("s_waitcnt vmcnt(0)" ::: "memory");
      __builtin_amdgcn_s_barrier();
    }
    bufc = (bufc == 2) ? 0 : bufc + 1;
    bufs = (bufs == 2) ? 0 : bufs + 1;
  }

  const int orow0 = bm * BM + wr * 128 + fq * 4;
  const int ocol0 = bn * BN + wc * 64 + fr;
#pragma unroll
  for (int n = 0; n < 4; ++n) {
    const int col = ocol0 + n * 16;
    const float bias = b2[col];
#pragma unroll
    for (int m = 0; m < 8; ++m) {
      const int row = orow0 + m * 16;
#pragma unroll
      for (int r = 0; r < 4; ++r)
        out[(size_t)(row + r) * NDIM + col] = acc[m][n][r] + bias;
    }
  }
}

extern "C" void kernel_launch(void* const* d_in, const int* in_sizes, int n_in,
                              void* d_out, int out_size, void* d_ws, size_t ws_size,
                              hipStream_t stream) {
  const float* x  = (const float*)d_in[0];
  const float* W1 = (const float*)d_in[1];
  const float* b1 = (const float*)d_in[2];
  const float* W2 = (const float*)d_in[3];
  const float* b2 = (const float*)d_in[4];
  float* out = (float*)d_out;

  unsigned short* Hb  = (unsigned short*)d_ws;
  unsigned short* W2b = (unsigned short*)((char*)d_ws + (size_t)NTOK * FFN * 2);

  hipLaunchKernelGGL(w2cvt_kernel, dim3((EMBED * KDIM / 4) / 256), dim3(256), 0,
                     stream, W2, W2b);
  hipLaunchKernelGGL(h_kernel, dim3(NTOK / TPB), dim3(512), 0, stream,
                     x, W1, b1, Hb);
  hipLaunchKernelGGL(gemm_kernel, dim3((NTOK / BM) * (NDIM / BN)), dim3(512), 0,
                     stream, Hb, W2b, b2, out);
}